// Round 6
// baseline (1171.738 us; speedup 1.0000x reference)
//
#include <hip/hip_runtime.h>

// ---------------- constants ----------------
#define N_NODES 65536
#define D_MODEL 256
#define DFF     1024
#define E1_N    1048576
#define E2_N    524288
#define ATT_SCALE 0.17677669529663687f   // 1/sqrt(32)
#define LN_EPS  1e-5f
#define KVSTRIDE 576                      // 64B scales + 256B k(int8) + 256B v(int8)

typedef __attribute__((ext_vector_type(8))) __bf16 bf16x8;
typedef __attribute__((ext_vector_type(4))) float  floatx4;
typedef __attribute__((ext_vector_type(4))) unsigned short ushortx4;
typedef __attribute__((ext_vector_type(8))) unsigned short ushortx8;

__device__ __forceinline__ float bf2f(unsigned short u) {
  return __uint_as_float(((unsigned)u) << 16);
}
__device__ __forceinline__ unsigned short f2bf(float f) {
  unsigned u = __float_as_uint(f);
  return (unsigned short)((u + 0x7FFFu + ((u >> 16) & 1u)) >> 16);
}
__device__ __forceinline__ void i8x4_to_f32(unsigned int u, float* o) {
  o[0] = (float)(signed char)(u & 0xFF);
  o[1] = (float)(signed char)((u >> 8) & 0xFF);
  o[2] = (float)(signed char)((u >> 16) & 0xFF);
  o[3] = (float)(signed char)(u >> 24);
}

// async global->LDS, 16B per lane; LDS dst is wave-uniform base (+lane*16 by HW)
__device__ __forceinline__ void gld_lds16(const void* g, void* l) {
  __builtin_amdgcn_global_load_lds(
      (const __attribute__((address_space(1))) unsigned int*)g,
      (__attribute__((address_space(3))) unsigned int*)l, 16, 0, 0);
}

// ---------------- prep kernels ----------------
// batched: 8 square 256x256 fp32 -> bf16 transposes in one launch (z selects)
struct TW8 {
  const float* w[8];
  unsigned short* o[8];
};
__global__ __launch_bounds__(256) void transpose8(TW8 t) {
  __shared__ float tile[32][33];
  const int z = blockIdx.z;
  const float* W = t.w[z];
  unsigned short* Wt = t.o[z];
  const int tx = threadIdx.x & 31;
  const int ty = threadIdx.x >> 5;  // 0..7
  const int r0 = blockIdx.y * 32;
  const int c0 = blockIdx.x * 32;
#pragma unroll
  for (int p = 0; p < 4; ++p) {
    const int r = ty + p * 8;
    tile[r][tx] = W[(size_t)(r0 + r) * 256 + c0 + tx];
  }
  __syncthreads();
#pragma unroll
  for (int p = 0; p < 4; ++p) {
    const int r = ty + p * 8;
    Wt[(size_t)(c0 + r) * 256 + r0 + tx] = f2bf(tile[tx][r]);
  }
}

// generic single transpose: W [K][Nc] fp32 -> Wt [Nc][K] bf16
__global__ __launch_bounds__(256) void transpose_w(const float* __restrict__ W,
                                                   unsigned short* __restrict__ Wt,
                                                   int K, int Nc) {
  __shared__ float tile[32][33];
  const int tx = threadIdx.x & 31;
  const int ty = threadIdx.x >> 5;
  const int r0 = blockIdx.y * 32;
  const int c0 = blockIdx.x * 32;
#pragma unroll
  for (int p = 0; p < 4; ++p) {
    const int r = ty + p * 8;
    tile[r][tx] = W[(size_t)(r0 + r) * Nc + c0 + tx];
  }
  __syncthreads();
#pragma unroll
  for (int p = 0; p < 4; ++p) {
    const int r = ty + p * 8;
    Wt[(size_t)(c0 + r) * K + r0 + tx] = f2bf(tile[tx][r]);
  }
}

// both fp32->bf16 casts (h -> buf2, mem -> buf3) in one launch
__global__ __launch_bounds__(256) void f2bf2_kernel(const float* __restrict__ in0,
                                                    unsigned short* __restrict__ out0,
                                                    const float* __restrict__ in1,
                                                    unsigned short* __restrict__ out1,
                                                    int half) {
  int i = blockIdx.x * 256 + threadIdx.x;
  const float* in = (i < half) ? in0 : in1;
  unsigned short* out = (i < half) ? out0 : out1;
  int k = (i < half) ? i : i - half;
  float4 v = ((const float4*)in)[k];
  ushortx4 o;
  o.x = f2bf(v.x); o.y = f2bf(v.y); o.z = f2bf(v.z); o.w = f2bf(v.w);
  ((ushortx4*)out)[k] = o;
}

__global__ __launch_bounds__(256) void zero_kernel(int* __restrict__ p, int n) {
  int i = blockIdx.x * 256 + threadIdx.x;
  if (i < n) p[i] = 0;
}

// ---------------- CSR build (both graphs per launch) ----------------
__global__ __launch_bounds__(256) void hist2_kernel(const int* __restrict__ d0,
                                                    int* __restrict__ c0,
                                                    const int* __restrict__ d1,
                                                    int* __restrict__ c1) {
  int e = blockIdx.x * 256 + threadIdx.x;
  if (e < E1_N) atomicAdd(&c0[d0[e]], 1);
  if (e < E2_N) atomicAdd(&c1[d1[e]], 1);
}

// 2 blocks, 1024 threads each: block b scans graph b's counts
__global__ __launch_bounds__(1024) void scan2_kernel(int* __restrict__ cnt0,
                                                     int* __restrict__ rs0,
                                                     int* __restrict__ cur0,
                                                     int* __restrict__ cnt1,
                                                     int* __restrict__ rs1,
                                                     int* __restrict__ cur1) {
  int* cnt = blockIdx.x ? cnt1 : cnt0;
  int* row_start = blockIdx.x ? rs1 : rs0;
  int* cur = blockIdx.x ? cur1 : cur0;
  const int total = blockIdx.x ? E2_N : E1_N;
  __shared__ int lds[1024];
  const int tid = threadIdx.x;
  const int base = tid * 64;
  int s = 0;
  for (int i = 0; i < 64; ++i) s += cnt[base + i];
  lds[tid] = s;
  __syncthreads();
  int v = s;
  for (int off = 1; off < 1024; off <<= 1) {
    int add = (tid >= off) ? lds[tid - off] : 0;
    __syncthreads();
    v += add;
    lds[tid] = v;
    __syncthreads();
  }
  int run = v - s;
  for (int i = 0; i < 64; ++i) {
    int c = cnt[base + i];
    row_start[base + i] = run;
    cur[base + i] = run;
    run += c;
  }
  if (tid == 1023) row_start[N_NODES] = total;
}

// scatter both graphs; intra payload packed as int2{src, etype}
__global__ __launch_bounds__(256) void scatter2_kernel(const int* __restrict__ s0,
                                                       const int* __restrict__ d0,
                                                       const int* __restrict__ et,
                                                       int* __restrict__ cur0,
                                                       int2* __restrict__ out0,
                                                       const int* __restrict__ s1,
                                                       const int* __restrict__ d1,
                                                       int* __restrict__ cur1,
                                                       int* __restrict__ out1) {
  int e = blockIdx.x * 256 + threadIdx.x;
  if (e < E1_N) {
    int p = atomicAdd(&cur0[d0[e]], 1);
    out0[p] = make_int2(s0[e], et[e]);
  }
  if (e < E2_N) {
    int p = atomicAdd(&cur1[d1[e]], 1);
    out1[p] = s1[e];
  }
}

// ---------------- GEMM: C[M][N] = A[M][K] @ Bt[N][K]^T, bf16 in ----------------
// 128x128 tile / block of 256 threads (4 waves, 2x2 of 64x64), BK=32.
// OUT_KVQ: per-row-per-head int8 quantization into KVSTRIDE-packed rows
// (head = n>>5, 16 heads over Ntot=512; scales f32 at row start).
template <bool BIAS, bool RELU, bool OUT_KVQ>
__global__ __launch_bounds__(256) void gemm_bf16(const unsigned short* __restrict__ A,
                                                 const unsigned short* __restrict__ Bt,
                                                 const float* __restrict__ bias,
                                                 void* __restrict__ C,
                                                 int K, int Ntot) {
  __shared__ __align__(16) unsigned short sA[128 * 32];
  __shared__ __align__(16) unsigned short sB[128 * 32];
  const int tid  = threadIdx.x;
  const int wave = tid >> 6;
  const int lane = tid & 63;
  const int m0 = blockIdx.y * 128;
  const int n0 = blockIdx.x * 128;

  floatx4 acc[4][4] = {};

  const int l4r = lane >> 2;        // 0..15: row within 16-row staging chunk
  const int l4c = (lane & 3) * 8;   // bf16 col offset within BK=32 (16B granule)
  const int fr = lane & 15;         // m/n within 16x16 tile
  const int fk = (lane >> 4) * 8;   // k offset of this lane-quad
  const int wy = (wave >> 1) * 64;  // wave's m offset
  const int wx = (wave & 1) * 64;   // wave's n offset

  for (int k0 = 0; k0 < K; k0 += 32) {
#pragma unroll
    for (int c = 0; c < 2; ++c) {
      const int row = wave * 32 + c * 16;
      gld_lds16(A  + ((size_t)(m0 + row + l4r) * K + k0 + l4c), &sA[row * 32]);
      gld_lds16(Bt + ((size_t)(n0 + row + l4r) * K + k0 + l4c), &sB[row * 32]);
    }
    __syncthreads();
    bf16x8 af[4], bfv[4];
#pragma unroll
    for (int i = 0; i < 4; ++i) af[i]  = *(const bf16x8*)&sA[(wy + i * 16 + fr) * 32 + fk];
#pragma unroll
    for (int j = 0; j < 4; ++j) bfv[j] = *(const bf16x8*)&sB[(wx + j * 16 + fr) * 32 + fk];
#pragma unroll
    for (int i = 0; i < 4; ++i)
#pragma unroll
      for (int j = 0; j < 4; ++j)
        acc[i][j] = __builtin_amdgcn_mfma_f32_16x16x32_bf16(af[i], bfv[j], acc[i][j], 0, 0, 0);
    __syncthreads();
  }

  // epilogue: D col(n) = lane&15, row(m) = (lane>>4)*4 + r
  const int coln = lane & 15;
  const int rowq = (lane >> 4) * 4;

  if (OUT_KVQ) {
    unsigned char* Cb = (unsigned char*)C;
#pragma unroll
    for (int i = 0; i < 4; ++i) {
#pragma unroll
      for (int jp = 0; jp < 2; ++jp) {
        const int head = ((n0 + wx) >> 5) + jp;  // 0..15 over Ntot=512
#pragma unroll
        for (int r = 0; r < 4; ++r) {
          float am = fmaxf(fabsf(acc[i][2 * jp][r]), fabsf(acc[i][2 * jp + 1][r]));
          am = fmaxf(am, __shfl_xor(am, 1));
          am = fmaxf(am, __shfl_xor(am, 2));
          am = fmaxf(am, __shfl_xor(am, 4));
          am = fmaxf(am, __shfl_xor(am, 8));
          const int m = m0 + wy + i * 16 + rowq + r;
          const float inv = am > 0.f ? 127.f / am : 0.f;
#pragma unroll
          for (int jj = 0; jj < 2; ++jj) {
            const int j = 2 * jp + jj;
            const int n = n0 + wx + j * 16 + coln;
            const int qv = __float2int_rn(acc[i][j][r] * inv);
            Cb[(size_t)m * KVSTRIDE + 64 + n] = (unsigned char)(signed char)qv;
          }
          if (coln == 0) {
            *(float*)(Cb + (size_t)m * KVSTRIDE + head * 4) = am * (1.f / 127.f);
          }
        }
      }
    }
  } else {
    unsigned short* Cs = (unsigned short*)C;
#pragma unroll
    for (int j = 0; j < 4; ++j) {
      const int n = n0 + wx + j * 16 + coln;
      float bval = 0.f;
      if (BIAS) bval = bias[n];
#pragma unroll
      for (int i = 0; i < 4; ++i) {
        const int mbase = m0 + wy + i * 16 + rowq;
#pragma unroll
        for (int r = 0; r < 4; ++r) {
          float v = acc[i][j][r] + bval;
          if (RELU) v = fmaxf(v, 0.f);
          Cs[(size_t)(mbase + r) * Ntot + n] = f2bf(v);
        }
      }
    }
  }
}

// ---------------- fused per-dst graph attention (int8 k/v gather) ----------------
// one wave per dst node, FOUR edges in flight per iteration:
// lane = edge-group(2b) x l(4b); lane covers 16 dims (head=l>>1, half=l&1).
// kv row (KVSTRIDE B): [16 f32 scales | k int8 256 | v int8 256].
// outp may alias qb (each wave reads only its own dst's q row before writing it).
template <bool HAS_REL>
__global__ __launch_bounds__(256) void attn_kernel(const unsigned short* qb,
                                                   const unsigned char* __restrict__ kvb,
                                                   const int* __restrict__ row_start,
                                                   const int2* __restrict__ s_se,
                                                   const int* __restrict__ s_src,
                                                   const float* __restrict__ ak_embed,
                                                   unsigned short* outp) {
  const int lane = threadIdx.x & 63;
  const int wave = threadIdx.x >> 6;
  const int dst  = blockIdx.x * 4 + wave;
  const int eg   = lane >> 4;   // edge slot 0..3
  const int l    = lane & 15;   // 16 lanes per edge; head = l>>1
  const int doff = l * 16;      // dims [l*16, l*16+16)

  const unsigned short* qrow = qb + (size_t)dst * 256 + doff;
  ushortx8 qu0 = *(const ushortx8*)qrow;
  ushortx8 qu1 = *(const ushortx8*)(qrow + 8);
  float q[16];
#pragma unroll
  for (int d = 0; d < 8; ++d) {
    q[d]     = bf2f(qu0[d]) * ATT_SCALE;   // pre-scale: e = (k.q + ak.q)*SCALE
    q[d + 8] = bf2f(qu1[d]) * ATT_SCALE;
  }

  float a[16];
#pragma unroll
  for (int d = 0; d < 16; ++d) a[d] = 0.f;
  float lsum = 0.f;

  const int beg = row_start[dst], end = row_start[dst + 1];
  for (int j = beg; j < end; j += 4) {
    const int e = j + eg;
    const bool valid = e < end;
    const int ecl = valid ? e : (end - 1);
    int src, et = 0;
    if (HAS_REL) {
      int2 se = s_se[ecl];
      src = se.x; et = se.y;
    } else {
      src = s_src[ecl];
    }
    const unsigned char* kvrow = kvb + (size_t)src * KVSTRIDE;
    const float ks = *(const float*)(kvrow + (l >> 1) * 4);
    const float vs = *(const float*)(kvrow + 32 + (l >> 1) * 4);
    uint4 ku = *(const uint4*)(kvrow + 64 + doff);
    uint4 vu = *(const uint4*)(kvrow + 320 + doff);
    float kf[16], vf[16];
    i8x4_to_f32(ku.x, kf + 0);  i8x4_to_f32(ku.y, kf + 4);
    i8x4_to_f32(ku.z, kf + 8);  i8x4_to_f32(ku.w, kf + 12);
    float dotk = 0.f;
#pragma unroll
    for (int d = 0; d < 16; ++d) dotk += kf[d] * q[d];
    float part = dotk * ks;
    if (HAS_REL) {
      const float* ak = ak_embed + (size_t)et * 32 + (l & 1) * 16;
      float4 a0 = *(const float4*)ak;
      float4 a1 = *(const float4*)(ak + 4);
      float4 a2 = *(const float4*)(ak + 8);
      float4 a3 = *(const float4*)(ak + 12);
      part += a0.x * q[0]  + a0.y * q[1]  + a0.z * q[2]  + a0.w * q[3]
            + a1.x * q[4]  + a1.y * q[5]  + a1.z * q[6]  + a1.w * q[7]
            + a2.x * q[8]  + a2.y * q[9]  + a2.z * q[10] + a2.w * q[11]
            + a3.x * q[12] + a3.y * q[13] + a3.z * q[14] + a3.w * q[15];
    }
    part += __shfl_xor(part, 1);  // pair-reduce: both lanes of head l>>1 hold score
    // e*SCALE ~ N(0,1): exp-safe without segment-max (softmax shift-invariant)
    const float pw = valid ? __expf(part) : 0.f;
    lsum += pw;
    i8x4_to_f32(vu.x, vf + 0);  i8x4_to_f32(vu.y, vf + 4);
    i8x4_to_f32(vu.z, vf + 8);  i8x4_to_f32(vu.w, vf + 12);
    const float pwv = pw * vs;
#pragma unroll
    for (int d = 0; d < 16; ++d) a[d] += pwv * vf[d];
  }
  // combine the four edge groups (same dims/head at same l)
  lsum += __shfl_xor(lsum, 16);
  lsum += __shfl_xor(lsum, 32);
#pragma unroll
  for (int d = 0; d < 16; ++d) {
    a[d] += __shfl_xor(a[d], 16);
    a[d] += __shfl_xor(a[d], 32);
  }
  const float inv = lsum > 0.f ? 1.f / lsum : 0.f;
  if (eg == 0) {
    ushortx8 o0, o1;
#pragma unroll
    for (int d = 0; d < 8; ++d) {
      o0[d] = f2bf(a[d] * inv);
      o1[d] = f2bf(a[d + 8] * inv);
    }
    unsigned short* orow = outp + (size_t)dst * 256 + doff;
    *(ushortx8*)orow = o0;
    *(ushortx8*)(orow + 8) = o1;
  }
}

// ---------------- residual + LayerNorm (wave per row, in-place safe) ----------------
template <bool WRITE_BF>
__global__ __launch_bounds__(256) void ln_kernel(const float* __restrict__ xin,
                                                 const unsigned short* __restrict__ oin,
                                                 const float* __restrict__ g,
                                                 const float* __restrict__ b,
                                                 float* __restrict__ xout,
                                                 unsigned short* __restrict__ bfout) {
  const int lane = threadIdx.x & 63;
  const int wave = threadIdx.x >> 6;
  const size_t row  = (size_t)blockIdx.x * 4 + wave;
  const size_t base = row * 256 + lane * 4;
  float4 xv = *(const float4*)(xin + base);
  ushortx4 ou = *(const ushortx4*)(oin + base);
  const float x0 = xv.x + bf2f(ou.x), x1 = xv.y + bf2f(ou.y),
              x2 = xv.z + bf2f(ou.z), x3 = xv.w + bf2f(ou.w);
  float sum = x0 + x1 + x2 + x3;
  float ss  = x0 * x0 + x1 * x1 + x2 * x2 + x3 * x3;
#pragma unroll
  for (int m = 1; m <= 32; m <<= 1) {
    sum += __shfl_xor(sum, m);
    ss  += __shfl_xor(ss, m);
  }
  const float mu  = sum * (1.f / 256.f);
  const float var = ss * (1.f / 256.f) - mu * mu;
  const float rs  = rsqrtf(var + LN_EPS);
  float4 gv = *(const float4*)(g + lane * 4);
  float4 bv = *(const float4*)(b + lane * 4);
  const float y0 = (x0 - mu) * rs * gv.x + bv.x;
  const float y1 = (x1 - mu) * rs * gv.y + bv.y;
  const float y2 = (x2 - mu) * rs * gv.z + bv.z;
  const float y3 = (x3 - mu) * rs * gv.w + bv.w;
  *(float4*)(xout + base) = make_float4(y0, y1, y2, y3);
  if (WRITE_BF) {
    ushortx4 yo;
    yo.x = f2bf(y0); yo.y = f2bf(y1); yo.z = f2bf(y2); yo.w = f2bf(y3);
    *(ushortx4*)(bfout + base) = yo;
  }
}

// ---------------- launch ----------------
extern "C" void kernel_launch(void* const* d_in, const int* in_sizes, int n_in,
                              void* d_out, int out_size, void* d_ws, size_t ws_size,
                              hipStream_t stream) {
  const float* h_in      = (const float*)d_in[0];
  const float* mem_in    = (const float*)d_in[1];
  const int*   src_intra = (const int*)d_in[2];
  const int*   dst_intra = (const int*)d_in[3];
  const int*   etype     = (const int*)d_in[4];
  const int*   src_inter = (const int*)d_in[5];
  const int*   dst_inter = (const int*)d_in[6];
  const float* Wq0 = (const float*)d_in[7];
  const float* Wk0 = (const float*)d_in[8];
  const float* Wv0 = (const float*)d_in[9];
  const float* Wo0 = (const float*)d_in[10];
  const float* Wq1 = (const float*)d_in[11];
  const float* Wk1 = (const float*)d_in[12];
  const float* Wv1 = (const float*)d_in[13];
  const float* Wo1 = (const float*)d_in[14];
  const float* akE = (const float*)d_in[15];
  const float* ln0_g = (const float*)d_in[16];
  const float* ln0_b = (const float*)d_in[17];
  const float* ln1_g = (const float*)d_in[18];
  const float* ln1_b = (const float*)d_in[19];
  const float* ln2_g = (const float*)d_in[20];
  const float* ln2_b = (const float*)d_in[21];
  const float* Wf1 = (const float*)d_in[22];
  const float* bf1 = (const float*)d_in[23];
  const float* Wf2 = (const float*)d_in[24];
  const float* bf2 = (const float*)d_in[25];

  char* p = (char*)d_ws;
  auto alloc = [&](size_t bytes) {
    char* r = p;
    p += (bytes + 255) & ~(size_t)255;
    return r;
  };

  unsigned short* wqkv0t = (unsigned short*)alloc((size_t)768 * 256 * 2);
  unsigned short* wo0t   = (unsigned short*)alloc((size_t)256 * 256 * 2);
  unsigned short* wq1t   = (unsigned short*)alloc((size_t)256 * 256 * 2);
  unsigned short* wkv1t  = (unsigned short*)alloc((size_t)512 * 256 * 2);
  unsigned short* wo1t   = (unsigned short*)alloc((size_t)256 * 256 * 2);
  unsigned short* wf1t   = (unsigned short*)alloc((size_t)1024 * 256 * 2);
  unsigned short* wf2t   = (unsigned short*)alloc((size_t)256 * 1024 * 2);

  int* cnt01 = (int*)alloc((size_t)2 * N_NODES * 4);  // cnt0 | cnt1 adjacent
  int* cnt0 = cnt01;
  int* cnt1 = cnt01 + N_NODES;
  int* rs0   = (int*)alloc((size_t)(N_NODES + 1) * 4);
  int* cur0  = (int*)alloc((size_t)N_NODES * 4);
  int* rs1   = (int*)alloc((size_t)(N_NODES + 1) * 4);
  int* cur1  = (int*)alloc((size_t)N_NODES * 4);
  int2* sse0 = (int2*)alloc((size_t)E1_N * 8);  // packed {src, etype}
  int* ssrc1 = (int*)alloc((size_t)E2_N * 4);

  // RegionA (128 MB), reused:
  //   phase1/2: [q 32MB (q0/attn0-out, then q1/attn1-out)] [kv0p 37MB] [kv1p 37MB]
  //             (wo0 output scratch = kv1p before it's filled; wo1 scratch = kv0p after attn1)
  //   phase3:   ffn hidden bf16 [N,1024] = full 128MB
  char* regionA = alloc((size_t)128 * 1024 * 1024);
  unsigned short* qbuf = (unsigned short*)regionA;                       // 32 MB
  unsigned char*  kv0p = (unsigned char*)(regionA + (size_t)33554432);   // 36.9 MB
  unsigned char*  kv1p = (unsigned char*)(regionA + (size_t)71303168);   // 36.9 MB
  unsigned short* hidden = (unsigned short*)regionA;
  // buf2: h_bf -> h1_bf -> ffn2 out
  unsigned short* buf2 = (unsigned short*)alloc((size_t)N_NODES * 256 * 2);
  // buf3: mem_bf -> h2_bf
  unsigned short* buf3 = (unsigned short*)alloc((size_t)N_NODES * 256 * 2);

  float* hcur = (float*)d_out;  // fp32 residual chain lives in d_out

  const int TB = 256;

  // ---- phase 0: weights, casts, CSR ----
  TW8 tw;
  tw.w[0] = Wq0; tw.o[0] = wqkv0t;
  tw.w[1] = Wk0; tw.o[1] = wqkv0t + 65536;
  tw.w[2] = Wv0; tw.o[2] = wqkv0t + 131072;
  tw.w[3] = Wo0; tw.o[3] = wo0t;
  tw.w[4] = Wq1; tw.o[4] = wq1t;
  tw.w[5] = Wk1; tw.o[5] = wkv1t;
  tw.w[6] = Wv1; tw.o[6] = wkv1t + 65536;
  tw.w[7] = Wo1; tw.o[7] = wo1t;
  transpose8<<<dim3(8, 8, 8), TB, 0, stream>>>(tw);
  transpose_w<<<dim3(32, 8), TB, 0, stream>>>(Wf1, wf1t, 256, 1024);
  transpose_w<<<dim3(8, 32), TB, 0, stream>>>(Wf2, wf2t, 1024, 256);

  f2bf2_kernel<<<32768, TB, 0, stream>>>(h_in, buf2, mem_in, buf3, N_NODES * 256 / 4);

  zero_kernel<<<512, TB, 0, stream>>>(cnt01, 2 * N_NODES);
  hist2_kernel<<<E1_N / 256, TB, 0, stream>>>(dst_intra, cnt0, dst_inter, cnt1);
  scan2_kernel<<<2, 1024, 0, stream>>>(cnt0, rs0, cur0, cnt1, rs1, cur1);
  scatter2_kernel<<<E1_N / 256, TB, 0, stream>>>(src_intra, dst_intra, etype, cur0, sse0,
                                                 src_inter, dst_inter, cur1, ssrc1);

  // ---- phase 1: intra attention ----
  gemm_bf16<false, false, false><<<dim3(2, 512), TB, 0, stream>>>(buf2, wqkv0t, nullptr, qbuf, 256, 256);
  gemm_bf16<false, false, true><<<dim3(4, 512), TB, 0, stream>>>(buf2, wqkv0t + 65536, nullptr, kv0p, 256, 512);
  attn_kernel<true><<<16384, TB, 0, stream>>>(qbuf, kv0p, rs0, sse0, nullptr, akE, qbuf);
  gemm_bf16<false, false, false><<<dim3(2, 512), TB, 0, stream>>>(qbuf, wo0t, nullptr, (unsigned short*)kv1p, 256, 256);
  ln_kernel<true><<<16384, TB, 0, stream>>>(h_in, (unsigned short*)kv1p, ln0_g, ln0_b, hcur, buf2);

  // ---- phase 2: inter attention ----
  gemm_bf16<false, false, false><<<dim3(2, 512), TB, 0, stream>>>(buf2, wq1t, nullptr, qbuf, 256, 256);
  gemm_bf16<false, false, true><<<dim3(4, 512), TB, 0, stream>>>(buf3, wkv1t, nullptr, kv1p, 256, 512);
  attn_kernel<false><<<16384, TB, 0, stream>>>(qbuf, kv1p, rs1, nullptr, ssrc1, nullptr, qbuf);
  gemm_bf16<false, false, false><<<dim3(2, 512), TB, 0, stream>>>(qbuf, wo1t, nullptr, (unsigned short*)kv0p, 256, 256);
  ln_kernel<true><<<16384, TB, 0, stream>>>(hcur, (unsigned short*)kv0p, ln1_g, ln1_b, hcur, buf3);

  // ---- phase 3: FFN ----
  gemm_bf16<true, true, false><<<dim3(8, 512), TB, 0, stream>>>(buf3, wf1t, bf1, hidden, 256, 1024);
  gemm_bf16<true, false, false><<<dim3(2, 512), TB, 0, stream>>>(hidden, wf2t, bf2, buf2, 1024, 256);
  ln_kernel<false><<<16384, TB, 0, stream>>>(hcur, buf2, ln2_g, ln2_b, hcur, nullptr);
}

// Round 7
// 1026.921 us; speedup vs baseline: 1.1410x; 1.1410x over previous
//
#include <hip/hip_runtime.h>

// ---------------- constants ----------------
#define N_NODES 65536
#define D_MODEL 256
#define DFF     1024
#define E1_N    1048576
#define E2_N    524288
#define ATT_SCALE 0.17677669529663687f   // 1/sqrt(32)
#define LN_EPS  1e-5f

typedef __attribute__((ext_vector_type(8))) __bf16 bf16x8;
typedef __attribute__((ext_vector_type(4))) float  floatx4;
typedef __attribute__((ext_vector_type(4))) unsigned short ushortx4;
typedef __attribute__((ext_vector_type(8))) unsigned short ushortx8;

__device__ __forceinline__ float bf2f(unsigned short u) {
  return __uint_as_float(((unsigned)u) << 16);
}
__device__ __forceinline__ unsigned short f2bf(float f) {
  unsigned u = __float_as_uint(f);
  return (unsigned short)((u + 0x7FFFu + ((u >> 16) & 1u)) >> 16);
}
__device__ __forceinline__ int dot4i8(unsigned a, unsigned b, int c) {
#if __has_builtin(__builtin_amdgcn_sdot4)
  return __builtin_amdgcn_sdot4((int)a, (int)b, c, false);
#else
  c += (int)(signed char)(a & 0xFF) * (int)(signed char)(b & 0xFF);
  c += (int)(signed char)((a >> 8) & 0xFF) * (int)(signed char)((b >> 8) & 0xFF);
  c += (int)(signed char)((a >> 16) & 0xFF) * (int)(signed char)((b >> 16) & 0xFF);
  c += (int)(signed char)(a >> 24) * (int)(signed char)(b >> 24);
  return c;
#endif
}
__device__ __forceinline__ unsigned pack4i8(float a, float b, float c, float d, float inv) {
  int r0 = __float2int_rn(a * inv) & 0xFF;
  int r1 = __float2int_rn(b * inv) & 0xFF;
  int r2 = __float2int_rn(c * inv) & 0xFF;
  int r3 = __float2int_rn(d * inv) & 0xFF;
  return (unsigned)(r0 | (r1 << 8) | (r2 << 16) | (r3 << 24));
}

// async global->LDS, 16B per lane; LDS dst is wave-uniform base (+lane*16 by HW)
__device__ __forceinline__ void gld_lds16(const void* g, void* l) {
  __builtin_amdgcn_global_load_lds(
      (const __attribute__((address_space(1))) unsigned int*)g,
      (__attribute__((address_space(3))) unsigned int*)l, 16, 0, 0);
}

// ---------------- prep kernels ----------------
// batched: 8 square 256x256 fp32 -> bf16 transposes in one launch (z selects)
struct TW8 {
  const float* w[8];
  unsigned short* o[8];
};
__global__ __launch_bounds__(256) void transpose8(TW8 t) {
  __shared__ float tile[32][33];
  const int z = blockIdx.z;
  const float* W = t.w[z];
  unsigned short* Wt = t.o[z];
  const int tx = threadIdx.x & 31;
  const int ty = threadIdx.x >> 5;  // 0..7
  const int r0 = blockIdx.y * 32;
  const int c0 = blockIdx.x * 32;
#pragma unroll
  for (int p = 0; p < 4; ++p) {
    const int r = ty + p * 8;
    tile[r][tx] = W[(size_t)(r0 + r) * 256 + c0 + tx];
  }
  __syncthreads();
#pragma unroll
  for (int p = 0; p < 4; ++p) {
    const int r = ty + p * 8;
    Wt[(size_t)(c0 + r) * 256 + r0 + tx] = f2bf(tile[tx][r]);
  }
}

// generic single transpose: W [K][Nc] fp32 -> Wt [Nc][K] bf16
__global__ __launch_bounds__(256) void transpose_w(const float* __restrict__ W,
                                                   unsigned short* __restrict__ Wt,
                                                   int K, int Nc) {
  __shared__ float tile[32][33];
  const int tx = threadIdx.x & 31;
  const int ty = threadIdx.x >> 5;
  const int r0 = blockIdx.y * 32;
  const int c0 = blockIdx.x * 32;
#pragma unroll
  for (int p = 0; p < 4; ++p) {
    const int r = ty + p * 8;
    tile[r][tx] = W[(size_t)(r0 + r) * Nc + c0 + tx];
  }
  __syncthreads();
#pragma unroll
  for (int p = 0; p < 4; ++p) {
    const int r = ty + p * 8;
    Wt[(size_t)(c0 + r) * K + r0 + tx] = f2bf(tile[tx][r]);
  }
}

// both fp32->bf16 casts (h -> buf2, mem -> buf3) in one launch
__global__ __launch_bounds__(256) void f2bf2_kernel(const float* __restrict__ in0,
                                                    unsigned short* __restrict__ out0,
                                                    const float* __restrict__ in1,
                                                    unsigned short* __restrict__ out1,
                                                    int half) {
  int i = blockIdx.x * 256 + threadIdx.x;
  const float* in = (i < half) ? in0 : in1;
  unsigned short* out = (i < half) ? out0 : out1;
  int k = (i < half) ? i : i - half;
  float4 v = ((const float4*)in)[k];
  ushortx4 o;
  o.x = f2bf(v.x); o.y = f2bf(v.y); o.z = f2bf(v.z); o.w = f2bf(v.w);
  ((ushortx4*)out)[k] = o;
}

__global__ __launch_bounds__(256) void zero_kernel(int* __restrict__ p, int n) {
  int i = blockIdx.x * 256 + threadIdx.x;
  if (i < n) p[i] = 0;
}

// ---------------- CSR build (both graphs per launch) ----------------
__global__ __launch_bounds__(256) void hist2_kernel(const int* __restrict__ d0,
                                                    int* __restrict__ c0,
                                                    const int* __restrict__ d1,
                                                    int* __restrict__ c1) {
  int e = blockIdx.x * 256 + threadIdx.x;
  if (e < E1_N) atomicAdd(&c0[d0[e]], 1);
  if (e < E2_N) atomicAdd(&c1[d1[e]], 1);
}

// 2 blocks, 1024 threads each: block b scans graph b's counts
__global__ __launch_bounds__(1024) void scan2_kernel(int* __restrict__ cnt0,
                                                     int* __restrict__ rs0,
                                                     int* __restrict__ cur0,
                                                     int* __restrict__ cnt1,
                                                     int* __restrict__ rs1,
                                                     int* __restrict__ cur1) {
  int* cnt = blockIdx.x ? cnt1 : cnt0;
  int* row_start = blockIdx.x ? rs1 : rs0;
  int* cur = blockIdx.x ? cur1 : cur0;
  const int total = blockIdx.x ? E2_N : E1_N;
  __shared__ int lds[1024];
  const int tid = threadIdx.x;
  const int base = tid * 64;
  int s = 0;
  for (int i = 0; i < 64; ++i) s += cnt[base + i];
  lds[tid] = s;
  __syncthreads();
  int v = s;
  for (int off = 1; off < 1024; off <<= 1) {
    int add = (tid >= off) ? lds[tid - off] : 0;
    __syncthreads();
    v += add;
    lds[tid] = v;
    __syncthreads();
  }
  int run = v - s;
  for (int i = 0; i < 64; ++i) {
    int c = cnt[base + i];
    row_start[base + i] = run;
    cur[base + i] = run;
    run += c;
  }
  if (tid == 1023) row_start[N_NODES] = total;
}

// scatter both graphs; intra payload packed as int2{src, etype}
__global__ __launch_bounds__(256) void scatter2_kernel(const int* __restrict__ s0,
                                                       const int* __restrict__ d0,
                                                       const int* __restrict__ et,
                                                       int* __restrict__ cur0,
                                                       int2* __restrict__ out0,
                                                       const int* __restrict__ s1,
                                                       const int* __restrict__ d1,
                                                       int* __restrict__ cur1,
                                                       int* __restrict__ out1) {
  int e = blockIdx.x * 256 + threadIdx.x;
  if (e < E1_N) {
    int p = atomicAdd(&cur0[d0[e]], 1);
    out0[p] = make_int2(s0[e], et[e]);
  }
  if (e < E2_N) {
    int p = atomicAdd(&cur1[d1[e]], 1);
    out1[p] = s1[e];
  }
}

// ---------------- GEMM: C[M][N] = A[M][K] @ Bt[N][K]^T, bf16 in ----------------
// 128x128 tile / block of 256 threads (4 waves, 2x2 of 64x64), BK=32.
// OUT_KVQ (Ntot=512): int8 rows kvq[m][512] (k 256 | v 256) + per-head scale
// pairs sbuf[m][16] = {ks0,vs0, ks1,vs1, ...} (head = n>>5; k-heads n<256).
template <bool BIAS, bool RELU, bool OUT_KVQ>
__global__ __launch_bounds__(256) void gemm_bf16(const unsigned short* __restrict__ A,
                                                 const unsigned short* __restrict__ Bt,
                                                 const float* __restrict__ bias,
                                                 void* __restrict__ C,
                                                 float* __restrict__ sbuf,
                                                 int K, int Ntot) {
  __shared__ __align__(16) unsigned short sA[128 * 32];
  __shared__ __align__(16) unsigned short sB[128 * 32];
  const int tid  = threadIdx.x;
  const int wave = tid >> 6;
  const int lane = tid & 63;
  const int m0 = blockIdx.y * 128;
  const int n0 = blockIdx.x * 128;

  floatx4 acc[4][4] = {};

  const int l4r = lane >> 2;        // 0..15: row within 16-row staging chunk
  const int l4c = (lane & 3) * 8;   // bf16 col offset within BK=32 (16B granule)
  const int fr = lane & 15;         // m/n within 16x16 tile
  const int fk = (lane >> 4) * 8;   // k offset of this lane-quad
  const int wy = (wave >> 1) * 64;  // wave's m offset
  const int wx = (wave & 1) * 64;   // wave's n offset

  for (int k0 = 0; k0 < K; k0 += 32) {
#pragma unroll
    for (int c = 0; c < 2; ++c) {
      const int row = wave * 32 + c * 16;
      gld_lds16(A  + ((size_t)(m0 + row + l4r) * K + k0 + l4c), &sA[row * 32]);
      gld_lds16(Bt + ((size_t)(n0 + row + l4r) * K + k0 + l4c), &sB[row * 32]);
    }
    __syncthreads();
    bf16x8 af[4], bfv[4];
#pragma unroll
    for (int i = 0; i < 4; ++i) af[i]  = *(const bf16x8*)&sA[(wy + i * 16 + fr) * 32 + fk];
#pragma unroll
    for (int j = 0; j < 4; ++j) bfv[j] = *(const bf16x8*)&sB[(wx + j * 16 + fr) * 32 + fk];
#pragma unroll
    for (int i = 0; i < 4; ++i)
#pragma unroll
      for (int j = 0; j < 4; ++j)
        acc[i][j] = __builtin_amdgcn_mfma_f32_16x16x32_bf16(af[i], bfv[j], acc[i][j], 0, 0, 0);
    __syncthreads();
  }

  // epilogue: D col(n) = lane&15, row(m) = (lane>>4)*4 + r
  const int coln = lane & 15;
  const int rowq = (lane >> 4) * 4;

  if (OUT_KVQ) {
    unsigned char* Cb = (unsigned char*)C;
#pragma unroll
    for (int i = 0; i < 4; ++i) {
#pragma unroll
      for (int jp = 0; jp < 2; ++jp) {
        const int head = ((n0 + wx) >> 5) + jp;  // 0..15 over Ntot=512
        const int pidx = (head < 8) ? head * 2 : (head - 8) * 2 + 1;
#pragma unroll
        for (int r = 0; r < 4; ++r) {
          float am = fmaxf(fabsf(acc[i][2 * jp][r]), fabsf(acc[i][2 * jp + 1][r]));
          am = fmaxf(am, __shfl_xor(am, 1));
          am = fmaxf(am, __shfl_xor(am, 2));
          am = fmaxf(am, __shfl_xor(am, 4));
          am = fmaxf(am, __shfl_xor(am, 8));
          const int m = m0 + wy + i * 16 + rowq + r;
          const float inv = am > 0.f ? 127.f / am : 0.f;
#pragma unroll
          for (int jj = 0; jj < 2; ++jj) {
            const int j = 2 * jp + jj;
            const int n = n0 + wx + j * 16 + coln;
            const int qv = __float2int_rn(acc[i][j][r] * inv);
            Cb[(size_t)m * 512 + n] = (unsigned char)(signed char)qv;
          }
          if (coln == 0) {
            sbuf[(size_t)m * 16 + pidx] = am * (1.f / 127.f);
          }
        }
      }
    }
  } else {
    unsigned short* Cs = (unsigned short*)C;
#pragma unroll
    for (int j = 0; j < 4; ++j) {
      const int n = n0 + wx + j * 16 + coln;
      float bval = 0.f;
      if (BIAS) bval = bias[n];
#pragma unroll
      for (int i = 0; i < 4; ++i) {
        const int mbase = m0 + wy + i * 16 + rowq;
#pragma unroll
        for (int r = 0; r < 4; ++r) {
          float v = acc[i][j][r] + bval;
          if (RELU) v = fmaxf(v, 0.f);
          Cs[(size_t)(mbase + r) * Ntot + n] = f2bf(v);
        }
      }
    }
  }
}

// ---------------- fused per-dst graph attention (int8 k/v, sdot4 scores) ----------------
// one wave per dst node, FOUR edges in flight per iteration:
// lane = edge-group(2b) x l(4b); lane covers 16 dims (head=l>>1).
// kv row: [k int8 256B | v int8 256B] (512B aligned); scales in sbuf[src][16]
// as {ks,vs} pairs per head (4 MB, L2/L3-resident).
// outp may alias qb (each wave reads only its own dst's q row before writing it).
template <bool HAS_REL>
__global__ __launch_bounds__(256) void attn_kernel(const unsigned short* qb,
                                                   const unsigned char* __restrict__ kvb,
                                                   const float* __restrict__ sbuf,
                                                   const int* __restrict__ row_start,
                                                   const int2* __restrict__ s_se,
                                                   const int* __restrict__ s_src,
                                                   const float* __restrict__ ak_embed,
                                                   unsigned short* outp) {
  const int lane = threadIdx.x & 63;
  const int wave = threadIdx.x >> 6;
  const int dst  = blockIdx.x * 4 + wave;
  const int eg   = lane >> 4;   // edge slot 0..3
  const int l    = lane & 15;   // 16 lanes per edge; head = l>>1
  const int doff = l * 16;      // dims [l*16, l*16+16)

  const unsigned short* qrow = qb + (size_t)dst * 256 + doff;
  ushortx8 qu0 = *(const ushortx8*)qrow;
  ushortx8 qu1 = *(const ushortx8*)(qrow + 8);
  float q[16];
#pragma unroll
  for (int d = 0; d < 8; ++d) {
    q[d]     = bf2f(qu0[d]) * ATT_SCALE;   // pre-scale: e = (k.q + ak.q)*SCALE
    q[d + 8] = bf2f(qu1[d]) * ATT_SCALE;
  }
  // per-head int8 quantization of q (head spans this lane + partner lane l^1)
  float qam = 0.f;
#pragma unroll
  for (int d = 0; d < 16; ++d) qam = fmaxf(qam, fabsf(q[d]));
  qam = fmaxf(qam, __shfl_xor(qam, 1));
  const float qs   = qam * (1.f / 127.f);
  const float qinv = qam > 0.f ? 127.f / qam : 0.f;
  unsigned qi[4];
#pragma unroll
  for (int c = 0; c < 4; ++c)
    qi[c] = pack4i8(q[4 * c], q[4 * c + 1], q[4 * c + 2], q[4 * c + 3], qinv);

  float a[16];
#pragma unroll
  for (int d = 0; d < 16; ++d) a[d] = 0.f;
  float lsum = 0.f;

  const int beg = row_start[dst], end = row_start[dst + 1];
  for (int j = beg; j < end; j += 4) {
    const int e = j + eg;
    const bool valid = e < end;
    const int ecl = valid ? e : (end - 1);
    int src, et = 0;
    if (HAS_REL) {
      int2 se = s_se[ecl];
      src = se.x; et = se.y;
    } else {
      src = s_src[ecl];
    }
    const unsigned char* kvrow = kvb + (size_t)src * 512;
    float2 sc = *(const float2*)(sbuf + (size_t)src * 16 + (l >> 1) * 2);  // {ks, vs}
    uint4 ku = *(const uint4*)(kvrow + doff);
    uint4 vu = *(const uint4*)(kvrow + 256 + doff);
    int idot = 0;
    idot = dot4i8(ku.x, qi[0], idot);
    idot = dot4i8(ku.y, qi[1], idot);
    idot = dot4i8(ku.z, qi[2], idot);
    idot = dot4i8(ku.w, qi[3], idot);
    float part = (float)idot * (sc.x * qs);
    if (HAS_REL) {
      const float* ak = ak_embed + (size_t)et * 32 + (l & 1) * 16;
      float4 a0 = *(const float4*)ak;
      float4 a1 = *(const float4*)(ak + 4);
      float4 a2 = *(const float4*)(ak + 8);
      float4 a3 = *(const float4*)(ak + 12);
      part += a0.x * q[0]  + a0.y * q[1]  + a0.z * q[2]  + a0.w * q[3]
            + a1.x * q[4]  + a1.y * q[5]  + a1.z * q[6]  + a1.w * q[7]
            + a2.x * q[8]  + a2.y * q[9]  + a2.z * q[10] + a2.w * q[11]
            + a3.x * q[12] + a3.y * q[13] + a3.z * q[14] + a3.w * q[15];
    }
    part += __shfl_xor(part, 1);  // pair-reduce: both lanes of head l>>1 hold score
    // e*SCALE ~ N(0,1): exp-safe without segment-max (softmax shift-invariant)
    const float pw = valid ? __expf(part) : 0.f;
    lsum += pw;
    const float pwv = pw * sc.y;
    // inline v decode, 4 floats live at a time
    {
      unsigned u = vu.x;
      a[0] += pwv * (float)(signed char)(u & 0xFF);
      a[1] += pwv * (float)(signed char)((u >> 8) & 0xFF);
      a[2] += pwv * (float)(signed char)((u >> 16) & 0xFF);
      a[3] += pwv * (float)(signed char)(u >> 24);
      u = vu.y;
      a[4] += pwv * (float)(signed char)(u & 0xFF);
      a[5] += pwv * (float)(signed char)((u >> 8) & 0xFF);
      a[6] += pwv * (float)(signed char)((u >> 16) & 0xFF);
      a[7] += pwv * (float)(signed char)(u >> 24);
      u = vu.z;
      a[8]  += pwv * (float)(signed char)(u & 0xFF);
      a[9]  += pwv * (float)(signed char)((u >> 8) & 0xFF);
      a[10] += pwv * (float)(signed char)((u >> 16) & 0xFF);
      a[11] += pwv * (float)(signed char)(u >> 24);
      u = vu.w;
      a[12] += pwv * (float)(signed char)(u & 0xFF);
      a[13] += pwv * (float)(signed char)((u >> 8) & 0xFF);
      a[14] += pwv * (float)(signed char)((u >> 16) & 0xFF);
      a[15] += pwv * (float)(signed char)(u >> 24);
    }
  }
  // combine the four edge groups (same dims/head at same l)
  lsum += __shfl_xor(lsum, 16);
  lsum += __shfl_xor(lsum, 32);
#pragma unroll
  for (int d = 0; d < 16; ++d) {
    a[d] += __shfl_xor(a[d], 16);
    a[d] += __shfl_xor(a[d], 32);
  }
  const float inv = lsum > 0.f ? 1.f / lsum : 0.f;
  if (eg == 0) {
    ushortx8 o0, o1;
#pragma unroll
    for (int d = 0; d < 8; ++d) {
      o0[d] = f2bf(a[d] * inv);
      o1[d] = f2bf(a[d + 8] * inv);
    }
    unsigned short* orow = outp + (size_t)dst * 256 + doff;
    *(ushortx8*)orow = o0;
    *(ushortx8*)(orow + 8) = o1;
  }
}

// ---------------- residual + LayerNorm (wave per row, in-place safe) ----------------
template <bool WRITE_BF>
__global__ __launch_bounds__(256) void ln_kernel(const float* __restrict__ xin,
                                                 const unsigned short* __restrict__ oin,
                                                 const float* __restrict__ g,
                                                 const float* __restrict__ b,
                                                 float* __restrict__ xout,
                                                 unsigned short* __restrict__ bfout) {
  const int lane = threadIdx.x & 63;
  const int wave = threadIdx.x >> 6;
  const size_t row  = (size_t)blockIdx.x * 4 + wave;
  const size_t base = row * 256 + lane * 4;
  float4 xv = *(const float4*)(xin + base);
  ushortx4 ou = *(const ushortx4*)(oin + base);
  const float x0 = xv.x + bf2f(ou.x), x1 = xv.y + bf2f(ou.y),
              x2 = xv.z + bf2f(ou.z), x3 = xv.w + bf2f(ou.w);
  float sum = x0 + x1 + x2 + x3;
  float ss  = x0 * x0 + x1 * x1 + x2 * x2 + x3 * x3;
#pragma unroll
  for (int m = 1; m <= 32; m <<= 1) {
    sum += __shfl_xor(sum, m);
    ss  += __shfl_xor(ss, m);
  }
  const float mu  = sum * (1.f / 256.f);
  const float var = ss * (1.f / 256.f) - mu * mu;
  const float rs  = rsqrtf(var + LN_EPS);
  float4 gv = *(const float4*)(g + lane * 4);
  float4 bv = *(const float4*)(b + lane * 4);
  const float y0 = (x0 - mu) * rs * gv.x + bv.x;
  const float y1 = (x1 - mu) * rs * gv.y + bv.y;
  const float y2 = (x2 - mu) * rs * gv.z + bv.z;
  const float y3 = (x3 - mu) * rs * gv.w + bv.w;
  *(float4*)(xout + base) = make_float4(y0, y1, y2, y3);
  if (WRITE_BF) {
    ushortx4 yo;
    yo.x = f2bf(y0); yo.y = f2bf(y1); yo.z = f2bf(y2); yo.w = f2bf(y3);
    *(ushortx4*)(bfout + base) = yo;
  }
}

// ---------------- launch ----------------
extern "C" void kernel_launch(void* const* d_in, const int* in_sizes, int n_in,
                              void* d_out, int out_size, void* d_ws, size_t ws_size,
                              hipStream_t stream) {
  const float* h_in      = (const float*)d_in[0];
  const float* mem_in    = (const float*)d_in[1];
  const int*   src_intra = (const int*)d_in[2];
  const int*   dst_intra = (const int*)d_in[3];
  const int*   etype     = (const int*)d_in[4];
  const int*   src_inter = (const int*)d_in[5];
  const int*   dst_inter = (const int*)d_in[6];
  const float* Wq0 = (const float*)d_in[7];
  const float* Wk0 = (const float*)d_in[8];
  const float* Wv0 = (const float*)d_in[9];
  const float* Wo0 = (const float*)d_in[10];
  const float* Wq1 = (const float*)d_in[11];
  const float* Wk1 = (const float*)d_in[12];
  const float* Wv1 = (const float*)d_in[13];
  const float* Wo1 = (const float*)d_in[14];
  const float* akE = (const float*)d_in[15];
  const float* ln0_g = (const float*)d_in[16];
  const float* ln0_b = (const float*)d_in[17];
  const float* ln1_g = (const float*)d_in[18];
  const float* ln1_b = (const float*)d_in[19];
  const float* ln2_g = (const float*)d_in[20];
  const float* ln2_b = (const float*)d_in[21];
  const float* Wf1 = (const float*)d_in[22];
  const float* bf1 = (const float*)d_in[23];
  const float* Wf2 = (const float*)d_in[24];
  const float* bf2 = (const float*)d_in[25];

  char* p = (char*)d_ws;
  auto alloc = [&](size_t bytes) {
    char* r = p;
    p += (bytes + 255) & ~(size_t)255;
    return r;
  };

  unsigned short* wqkv0t = (unsigned short*)alloc((size_t)768 * 256 * 2);
  unsigned short* wo0t   = (unsigned short*)alloc((size_t)256 * 256 * 2);
  unsigned short* wq1t   = (unsigned short*)alloc((size_t)256 * 256 * 2);
  unsigned short* wkv1t  = (unsigned short*)alloc((size_t)512 * 256 * 2);
  unsigned short* wo1t   = (unsigned short*)alloc((size_t)256 * 256 * 2);
  unsigned short* wf1t   = (unsigned short*)alloc((size_t)1024 * 256 * 2);
  unsigned short* wf2t   = (unsigned short*)alloc((size_t)256 * 1024 * 2);

  int* cnt01 = (int*)alloc((size_t)2 * N_NODES * 4);  // cnt0 | cnt1 adjacent
  int* cnt0 = cnt01;
  int* cnt1 = cnt01 + N_NODES;
  int* rs0   = (int*)alloc((size_t)(N_NODES + 1) * 4);
  int* cur0  = (int*)alloc((size_t)N_NODES * 4);
  int* rs1   = (int*)alloc((size_t)(N_NODES + 1) * 4);
  int* cur1  = (int*)alloc((size_t)N_NODES * 4);
  int2* sse0 = (int2*)alloc((size_t)E1_N * 8);  // packed {src, etype}
  int* ssrc1 = (int*)alloc((size_t)E2_N * 4);

  // RegionA (128 MB), reused:
  //   phase1/2: [qbuf 32MB] [kv0q 32MB] [kv1q 32MB] [scratch 32MB (wo0/wo1 out)]
  //   phase3:   ffn hidden bf16 [N,1024] = full 128MB
  char* regionA = alloc((size_t)128 * 1024 * 1024);
  unsigned short* qbuf    = (unsigned short*)regionA;                      // 32 MB
  unsigned char*  kv0q    = (unsigned char*)(regionA + (size_t)33554432);  // 32 MB
  unsigned char*  kv1q    = (unsigned char*)(regionA + (size_t)67108864);  // 32 MB
  unsigned short* scratch = (unsigned short*)(regionA + (size_t)100663296);
  unsigned short* hidden  = (unsigned short*)regionA;
  float* sbuf0 = (float*)alloc((size_t)N_NODES * 16 * 4);  // 4 MB scales
  float* sbuf1 = (float*)alloc((size_t)N_NODES * 16 * 4);  // 4 MB scales
  // buf2: h_bf -> h1_bf -> ffn2 out
  unsigned short* buf2 = (unsigned short*)alloc((size_t)N_NODES * 256 * 2);
  // buf3: mem_bf -> h2_bf
  unsigned short* buf3 = (unsigned short*)alloc((size_t)N_NODES * 256 * 2);

  float* hcur = (float*)d_out;  // fp32 residual chain lives in d_out

  const int TB = 256;

  // ---- phase 0: weights, casts, CSR ----
  TW8 tw;
  tw.w[0] = Wq0; tw.o[0] = wqkv0t;
  tw.w[1] = Wk0; tw.o[1] = wqkv0t + 65536;
  tw.w[2] = Wv0; tw.o[2] = wqkv0t + 131072;
  tw.w[3] = Wo0; tw.o[3] = wo0t;
  tw.w[4] = Wq1; tw.o[4] = wq1t;
  tw.w[5] = Wk1; tw.o[5] = wkv1t;
  tw.w[6] = Wv1; tw.o[6] = wkv1t + 65536;
  tw.w[7] = Wo1; tw.o[7] = wo1t;
  transpose8<<<dim3(8, 8, 8), TB, 0, stream>>>(tw);
  transpose_w<<<dim3(32, 8), TB, 0, stream>>>(Wf1, wf1t, 256, 1024);
  transpose_w<<<dim3(8, 32), TB, 0, stream>>>(Wf2, wf2t, 1024, 256);

  f2bf2_kernel<<<32768, TB, 0, stream>>>(h_in, buf2, mem_in, buf3, N_NODES * 256 / 4);

  zero_kernel<<<512, TB, 0, stream>>>(cnt01, 2 * N_NODES);
  hist2_kernel<<<E1_N / 256, TB, 0, stream>>>(dst_intra, cnt0, dst_inter, cnt1);
  scan2_kernel<<<2, 1024, 0, stream>>>(cnt0, rs0, cur0, cnt1, rs1, cur1);
  scatter2_kernel<<<E1_N / 256, TB, 0, stream>>>(src_intra, dst_intra, etype, cur0, sse0,
                                                 src_inter, dst_inter, cur1, ssrc1);

  // ---- phase 1: intra attention ----
  gemm_bf16<false, false, false><<<dim3(2, 512), TB, 0, stream>>>(buf2, wqkv0t, nullptr, qbuf, nullptr, 256, 256);
  gemm_bf16<false, false, true><<<dim3(4, 512), TB, 0, stream>>>(buf2, wqkv0t + 65536, nullptr, kv0q, sbuf0, 256, 512);
  attn_kernel<true><<<16384, TB, 0, stream>>>(qbuf, kv0q, sbuf0, rs0, sse0, nullptr, akE, qbuf);
  gemm_bf16<false, false, false><<<dim3(2, 512), TB, 0, stream>>>(qbuf, wo0t, nullptr, scratch, nullptr, 256, 256);
  ln_kernel<true><<<16384, TB, 0, stream>>>(h_in, scratch, ln0_g, ln0_b, hcur, buf2);

  // ---- phase 2: inter attention ----
  gemm_bf16<false, false, false><<<dim3(2, 512), TB, 0, stream>>>(buf2, wq1t, nullptr, qbuf, nullptr, 256, 256);
  gemm_bf16<false, false, true><<<dim3(4, 512), TB, 0, stream>>>(buf3, wkv1t, nullptr, kv1q, sbuf1, 256, 512);
  attn_kernel<false><<<16384, TB, 0, stream>>>(qbuf, kv1q, sbuf1, rs1, nullptr, ssrc1, nullptr, qbuf);
  gemm_bf16<false, false, false><<<dim3(2, 512), TB, 0, stream>>>(qbuf, wo1t, nullptr, scratch, nullptr, 256, 256);
  ln_kernel<true><<<16384, TB, 0, stream>>>(hcur, scratch, ln1_g, ln1_b, hcur, buf3);

  // ---- phase 3: FFN ----
  gemm_bf16<true, true, false><<<dim3(8, 512), TB, 0, stream>>>(buf3, wf1t, bf1, hidden, nullptr, 256, 1024);
  gemm_bf16<true, false, false><<<dim3(2, 512), TB, 0, stream>>>(hidden, wf2t, bf2, buf2, nullptr, 1024, 256);
  ln_kernel<false><<<16384, TB, 0, stream>>>(hcur, buf2, ln2_g, ln2_b, hcur, nullptr);
}